// Round 2
// baseline (4966.091 us; speedup 1.0000x reference)
//
#include <hip/hip_runtime.h>
#include <hip/hip_cooperative_groups.h>

namespace cg = cooperative_groups;

#define NROWS 65536
#define DIM   512
#define INV_N (1.0f/65536.0f)
#define INV_TEMP 0.1f
#define T_ITERS 10

typedef __attribute__((ext_vector_type(8))) short bf16x8;   // 8 bf16 = 4 VGPR (MFMA A/B frag)
typedef __attribute__((ext_vector_type(4))) float f32x4;    // MFMA C/D frag

// ws layout (floats). zero_k zeroes [OFF_G, OFF_S) = G + scal + cs contiguously.
#define OFF_G    0
#define OFF_SCAL 262144
#define OFF_CS   262208
#define OFF_S    262720
#define OFF_P    (OFF_S  + 262144)
#define OFF_T1   (OFF_P  + 262144)
#define OFF_T2   (OFF_T1 + 262144)
#define OFF_CV   (OFF_T2 + 262144)
#define OFF_MH   (OFF_CV + 262144)
#define OFF_BIAS (OFF_MH + 512)
#define OFF_WCH  (OFF_BIAS + 512)   // WCt hi: 512x512 u16 = 131072 floats
#define OFF_WCL  (OFF_WCH + 131072) // WCt lo
// total = OFF_WCL + 131072 = 1836608 floats = 7.35 MB (round 1 proved >=23 MB available)

__device__ __forceinline__ unsigned short bf_hi(float x) {
    return (unsigned short)(__float_as_uint(x) >> 16);      // truncation split: hi+lo error ~2^-16
}
__device__ __forceinline__ float bf_f(unsigned short h) {
    return __uint_as_float(((unsigned)h) << 16);
}

// ---------------------------------------------------------------------------
// zero G (1MB) + scal (64) + cs (512): 262720 floats = 65680 float4
__global__ __launch_bounds__(256) void zero_k(float* __restrict__ ws) {
    int idx = blockIdx.x * 256 + threadIdx.x;
    if (idx < 65680) reinterpret_cast<float4*>(ws)[idx] = make_float4(0.f, 0.f, 0.f, 0.f);
}

// ---------------------------------------------------------------------------
// Gram G += X^T X via split-bf16 MFMA. Upper-tri 128x128 tiles (10) x 32 row-chunks
// of 2048. atomicAdd fp32 partials into zeroed G. Diagonal blocks also fold the
// column-sum (cs) so no separate colsum kernel/pass is needed.
__global__ __launch_bounds__(256, 2) void gram_k(const float* __restrict__ in,
                                                 float* __restrict__ G,
                                                 float* __restrict__ cs) {
    __shared__ unsigned short Ah[128][40], Al[128][40], Bh[128][40], Bl[128][40];
    int u = blockIdx.x, z = blockIdx.y;
    int bi, bj;
    if (u < 4)      { bi = 0; bj = u; }
    else if (u < 7) { bi = 1; bj = u - 3; }
    else if (u < 9) { bi = 2; bj = u - 5; }
    else            { bi = 3; bj = 3; }
    bool diag = (bi == bj);
    int ci0 = bi * 128, cj0 = bj * 128;
    int t = threadIdx.x;
    int d = t & 127, nh = (t >> 7) * 16;          // staging: column d, n-half
    const float* baseA = in + (size_t)z * 2048 * DIM + ci0 + d;
    const float* baseB = in + (size_t)z * 2048 * DIM + cj0 + d;
    int lane = t & 63, w = t >> 6;
    int wr = (w >> 1) * 64, wc = (w & 1) * 64;    // wave quadrant of 128x128
    int fr = lane & 15, kg = lane >> 4;           // frag row/col sel, k-group
    f32x4 acc[4][4];
#pragma unroll
    for (int i = 0; i < 4; ++i)
#pragma unroll
        for (int j = 0; j < 4; ++j) acc[i][j] = (f32x4){0.f, 0.f, 0.f, 0.f};
    float pA[16], pB[16];
    float csum = 0.f;
#pragma unroll
    for (int j = 0; j < 16; ++j) pA[j] = baseA[(size_t)(nh + j) * DIM];
    if (!diag) {
#pragma unroll
        for (int j = 0; j < 16; ++j) pB[j] = baseB[(size_t)(nh + j) * DIM];
    }
    for (int s = 0; s < 64; ++s) {                // 64 k-steps of 32 rows = 2048
        __syncthreads();
        if (diag) {
#pragma unroll
            for (int j = 0; j < 16; ++j) csum += pA[j];
        }
#pragma unroll
        for (int gq = 0; gq < 2; ++gq) {
            unsigned hw[4], lw[4];
#pragma unroll
            for (int q = 0; q < 4; ++q) {
                float x0 = pA[gq * 8 + 2 * q], x1 = pA[gq * 8 + 2 * q + 1];
                unsigned short h0 = bf_hi(x0), h1 = bf_hi(x1);
                unsigned short l0 = bf_hi(x0 - bf_f(h0)), l1 = bf_hi(x1 - bf_f(h1));
                hw[q] = (unsigned)h0 | ((unsigned)h1 << 16);
                lw[q] = (unsigned)l0 | ((unsigned)l1 << 16);
            }
            *reinterpret_cast<uint4*>(&Ah[d][nh + 8 * gq]) = make_uint4(hw[0], hw[1], hw[2], hw[3]);
            *reinterpret_cast<uint4*>(&Al[d][nh + 8 * gq]) = make_uint4(lw[0], lw[1], lw[2], lw[3]);
        }
        if (!diag) {
#pragma unroll
            for (int gq = 0; gq < 2; ++gq) {
                unsigned hw[4], lw[4];
#pragma unroll
                for (int q = 0; q < 4; ++q) {
                    float x0 = pB[gq * 8 + 2 * q], x1 = pB[gq * 8 + 2 * q + 1];
                    unsigned short h0 = bf_hi(x0), h1 = bf_hi(x1);
                    unsigned short l0 = bf_hi(x0 - bf_f(h0)), l1 = bf_hi(x1 - bf_f(h1));
                    hw[q] = (unsigned)h0 | ((unsigned)h1 << 16);
                    lw[q] = (unsigned)l0 | ((unsigned)l1 << 16);
                }
                *reinterpret_cast<uint4*>(&Bh[d][nh + 8 * gq]) = make_uint4(hw[0], hw[1], hw[2], hw[3]);
                *reinterpret_cast<uint4*>(&Bl[d][nh + 8 * gq]) = make_uint4(lw[0], lw[1], lw[2], lw[3]);
            }
        }
        __syncthreads();
        if (s + 1 < 64) {                          // prefetch next step (overlaps MFMA)
#pragma unroll
            for (int j = 0; j < 16; ++j)
                pA[j] = baseA[(size_t)((s + 1) * 32 + nh + j) * DIM];
            if (!diag) {
#pragma unroll
                for (int j = 0; j < 16; ++j)
                    pB[j] = baseB[(size_t)((s + 1) * 32 + nh + j) * DIM];
            }
        }
        const unsigned short (*pBh)[40] = diag ? Ah : Bh;
        const unsigned short (*pBl)[40] = diag ? Al : Bl;
        bf16x8 ah[4], al4[4], bh4[4], bl4[4];
#pragma unroll
        for (int f = 0; f < 4; ++f) {
            ah[f]  = *reinterpret_cast<const bf16x8*>(&Ah[wr + f * 16 + fr][kg * 8]);
            al4[f] = *reinterpret_cast<const bf16x8*>(&Al[wr + f * 16 + fr][kg * 8]);
            bh4[f] = *reinterpret_cast<const bf16x8*>(&pBh[wc + f * 16 + fr][kg * 8]);
            bl4[f] = *reinterpret_cast<const bf16x8*>(&pBl[wc + f * 16 + fr][kg * 8]);
        }
#pragma unroll
        for (int i = 0; i < 4; ++i)
#pragma unroll
            for (int j = 0; j < 4; ++j) {          // 3-term split: hh + hl + lh (drop ll ~2^-18)
                f32x4 c = acc[i][j];
                c = __builtin_amdgcn_mfma_f32_16x16x32_bf16(ah[i],  bh4[j], c, 0, 0, 0);
                c = __builtin_amdgcn_mfma_f32_16x16x32_bf16(ah[i],  bl4[j], c, 0, 0, 0);
                c = __builtin_amdgcn_mfma_f32_16x16x32_bf16(al4[i], bh4[j], c, 0, 0, 0);
                acc[i][j] = c;
            }
    }
    // C/D layout (m89-verified): col = lane&15, row = (lane>>4)*4 + reg
#pragma unroll
    for (int i = 0; i < 4; ++i) {
        int row = ci0 + wr + i * 16 + kg * 4;
#pragma unroll
        for (int j = 0; j < 4; ++j) {
            int col = cj0 + wc + j * 16 + fr;
#pragma unroll
            for (int r = 0; r < 4; ++r)
                atomicAdd(&G[(size_t)(row + r) * DIM + col], acc[i][j][r]);
        }
    }
    if (diag) atomicAdd(&cs[ci0 + d], csum);
}

// ---------------------------------------------------------------------------
// 512x512x512 fp32 tile-GEMM body (round-1-verified), tile = 32x32 at index tid.
// mode 0: C=op(A)@B; 1: C=1.5C-0.5acc (NS update); 2: store + diag-trace atomic;
// 3: WCt split-bf16 transposed store (no C).
__device__ void gemm_tile(const float* __restrict__ A, int ta,
                          const float* __restrict__ B,
                          float* C, int tile, int mode, float* ws) {
    __shared__ float As[32][36];
    __shared__ float Bs[32][36];
    int m0 = (tile >> 4) * 32, n0 = (tile & 15) * 32;
    int t = threadIdx.x;
    int tx = t & 15, ty = t >> 4;
    int lr = t >> 3, lc = (t & 7) * 4;
    float acc00 = 0.f, acc01 = 0.f, acc10 = 0.f, acc11 = 0.f;
    float4 av, bv;
    av = ta ? *reinterpret_cast<const float4*>(&A[(size_t)lr * DIM + m0 + lc])
            : *reinterpret_cast<const float4*>(&A[(size_t)(m0 + lr) * DIM + lc]);
    bv = *reinterpret_cast<const float4*>(&B[(size_t)lr * DIM + n0 + lc]);
    for (int k0 = 0; k0 < DIM; k0 += 32) {
        __syncthreads();
        if (ta) {
            *reinterpret_cast<float4*>(&As[lr][lc]) = av;
        } else {
            As[lc + 0][lr] = av.x; As[lc + 1][lr] = av.y;
            As[lc + 2][lr] = av.z; As[lc + 3][lr] = av.w;
        }
        *reinterpret_cast<float4*>(&Bs[lr][lc]) = bv;
        __syncthreads();
        if (k0 + 32 < DIM) {
            av = ta ? *reinterpret_cast<const float4*>(&A[(size_t)(k0 + 32 + lr) * DIM + m0 + lc])
                    : *reinterpret_cast<const float4*>(&A[(size_t)(m0 + lr) * DIM + k0 + 32 + lc]);
            bv = *reinterpret_cast<const float4*>(&B[(size_t)(k0 + 32 + lr) * DIM + n0 + lc]);
        }
#pragma unroll
        for (int k = 0; k < 32; ++k) {
            float a0 = As[k][2 * ty], a1 = As[k][2 * ty + 1];
            float b0 = Bs[k][2 * tx], b1 = Bs[k][2 * tx + 1];
            acc00 = fmaf(a0, b0, acc00); acc01 = fmaf(a0, b1, acc01);
            acc10 = fmaf(a1, b0, acc10); acc11 = fmaf(a1, b1, acc11);
        }
    }
    int m = m0 + 2 * ty, n = n0 + 2 * tx;
    size_t i00 = (size_t)m * DIM + n, i10 = (size_t)(m + 1) * DIM + n;
    if (mode == 0) {
        C[i00] = acc00; C[i00 + 1] = acc01; C[i10] = acc10; C[i10 + 1] = acc11;
    } else if (mode == 1) {
        C[i00]     = 1.5f * C[i00]     - 0.5f * acc00;
        C[i00 + 1] = 1.5f * C[i00 + 1] - 0.5f * acc01;
        C[i10]     = 1.5f * C[i10]     - 0.5f * acc10;
        C[i10 + 1] = 1.5f * C[i10 + 1] - 0.5f * acc11;
    } else if (mode == 2) {
        C[i00] = acc00; C[i00 + 1] = acc01; C[i10] = acc10; C[i10 + 1] = acc11;
        if (m == n) atomicAdd(ws + OFF_SCAL, (acc00 + acc11) * INV_N);
    } else {
        unsigned short* WCth = (unsigned short*)(ws + OFF_WCH);
        unsigned short* WCtl = (unsigned short*)(ws + OFF_WCL);
        float istr = 1.0f / sqrtf(ws[OFF_SCAL]);
        float v;
        unsigned short h;
        v = acc00 * istr; h = bf_hi(v);
        WCth[(size_t)n * DIM + m] = h;           WCtl[(size_t)n * DIM + m] = bf_hi(v - bf_f(h));
        v = acc01 * istr; h = bf_hi(v);
        WCth[(size_t)(n + 1) * DIM + m] = h;     WCtl[(size_t)(n + 1) * DIM + m] = bf_hi(v - bf_f(h));
        v = acc10 * istr; h = bf_hi(v);
        WCth[(size_t)n * DIM + m + 1] = h;       WCtl[(size_t)n * DIM + m + 1] = bf_hi(v - bf_f(h));
        v = acc11 * istr; h = bf_hi(v);
        WCth[(size_t)(n + 1) * DIM + m + 1] = h; WCtl[(size_t)(n + 1) * DIM + m + 1] = bf_hi(v - bf_f(h));
    }
}

// ---------------------------------------------------------------------------
// Cooperative chain: mirror G -> T1=G@W (+mh) -> CV=W^T T1 (+trace) -> S,P ->
// 10x NS -> WCt(hi/lo) + bias. One launch replaces ~28.
__global__ __launch_bounds__(256) void coop_k(float* ws, const float* __restrict__ W) {
    cg::grid_group g = cg::this_grid();
    float* G  = ws + OFF_G;   float* scal = ws + OFF_SCAL;
    float* cs = ws + OFF_CS;  float* S    = ws + OFF_S;
    float* P  = ws + OFF_P;   float* T1   = ws + OFF_T1;
    float* T2 = ws + OFF_T2;  float* CV   = ws + OFF_CV;
    float* mh = ws + OFF_MH;  float* bias = ws + OFF_BIAS;
    int b = blockIdx.x, t = threadIdx.x;
    int gtid = b * 256 + t;
    // S0: mirror upper->lower (zeroed lower tiles + asym atomics both overwritten)
#pragma unroll
    for (int e = 0; e < 4; ++e) {
        int idx = gtid * 4 + e;
        int i = idx >> 9, j = idx & 511;
        if (i < j) G[(size_t)j * DIM + i] = G[idx];
    }
    g.sync();
    // S1: T1 = G @ W ; block0: mh = cs@W / n
    gemm_tile(G, 0, W, T1, b, 0, ws);
    if (b == 0) {
        for (int c = t; c < DIM; c += 256) {
            float s = 0.f;
            for (int k = 0; k < DIM; ++k) s = fmaf(cs[k], W[(size_t)k * DIM + c], s);
            mh[c] = s * INV_N;
        }
    }
    g.sync();
    // S2: CV = W^T @ T1 (+ diag trace/n atomics); block0: scal += 51.2 - sum(mh^2)
    gemm_tile(W, 1, T1, CV, b, 2, ws);
    if (b == 0) {
        __shared__ float red[256];
        red[t] = mh[t] * mh[t] + mh[t + 256] * mh[t + 256];
        __syncthreads();
        for (int o = 128; o > 0; o >>= 1) { if (t < o) red[t] += red[t + o]; __syncthreads(); }
        if (t == 0) atomicAdd(scal, 51.2f - red[0]);
    }
    g.sync();
    // S3: S = (CV/n - mh mh^T + I/temp)/tr ; P = I
    {
        float invtr = 1.0f / scal[0];
#pragma unroll
        for (int e = 0; e < 4; ++e) {
            int idx = gtid * 4 + e;
            int i = idx >> 9, j = idx & 511;
            float v = CV[idx] * INV_N - mh[i] * mh[j] + ((i == j) ? INV_TEMP : 0.f);
            S[idx] = v * invtr;
            P[idx] = (i == j) ? 1.f : 0.f;
        }
    }
    g.sync();
    for (int it = 0; it < T_ITERS; ++it) {
        gemm_tile(P, 0, P, T1, b, 0, ws);
        gemm_tile(P, 0, S, T2, b, 0, ws);
        g.sync();
        gemm_tile(T1, 0, T2, P, b, 1, ws);   // P = 1.5P - 0.5*(P@P)@(P@S)
        g.sync();
    }
    // S4: WCt = (W@P*istr)^T as bf16 hi/lo ; block0: bias = mh@P*istr
    gemm_tile(W, 0, P, nullptr, b, 3, ws);
    if (b == 0) {
        float istr = 1.0f / sqrtf(scal[0]);
        for (int c = t; c < DIM; c += 256) {
            float s = 0.f;
            for (int k = 0; k < DIM; ++k) s = fmaf(mh[k], P[(size_t)k * DIM + c], s);
            bias[c] = s * istr;
        }
    }
}

// ---------------------------------------------------------------------------
// OUT = IN @ WC - bias, split-bf16 MFMA, 128x128 tiles, K=512 in 8 steps of 64.
// B (WCt) is pre-converted bf16 hi/lo [n][k] -> conversion-free b128 staging.
__global__ __launch_bounds__(256, 2) void out_k(const float* __restrict__ in,
                                                const unsigned short* __restrict__ WCth,
                                                const unsigned short* __restrict__ WCtl,
                                                const float* __restrict__ bias,
                                                float* __restrict__ out) {
    __shared__ unsigned short Ah[128][72], Al[128][72], Bh[128][72], Bl[128][72];
    int n0 = blockIdx.x * 128, m0 = blockIdx.y * 128;
    int t = threadIdx.x;
    int lane = t & 63, w = t >> 6;
    int wr = (w >> 1) * 64, wc = (w & 1) * 64;
    int fr = lane & 15, kg = lane >> 4;
    int am = t >> 4, aq = (t & 15) * 4;
    int bn = t >> 3, bc = (t & 7) * 8;
    f32x4 acc[4][4];
#pragma unroll
    for (int i = 0; i < 4; ++i)
#pragma unroll
        for (int j = 0; j < 4; ++j) acc[i][j] = (f32x4){0.f, 0.f, 0.f, 0.f};
    float4 pa[8]; uint4 pbh[4], pbl[4];
#pragma unroll
    for (int p = 0; p < 8; ++p)
        pa[p] = *reinterpret_cast<const float4*>(&in[(size_t)(m0 + p * 16 + am) * DIM + aq]);
#pragma unroll
    for (int p = 0; p < 4; ++p) {
        pbh[p] = *reinterpret_cast<const uint4*>(&WCth[(size_t)(n0 + p * 32 + bn) * DIM + bc]);
        pbl[p] = *reinterpret_cast<const uint4*>(&WCtl[(size_t)(n0 + p * 32 + bn) * DIM + bc]);
    }
    for (int s = 0; s < 8; ++s) {
        __syncthreads();
#pragma unroll
        for (int p = 0; p < 8; ++p) {
            float4 v = pa[p];
            unsigned short h0 = bf_hi(v.x), h1 = bf_hi(v.y), h2 = bf_hi(v.z), h3 = bf_hi(v.w);
            unsigned short l0 = bf_hi(v.x - bf_f(h0)), l1 = bf_hi(v.y - bf_f(h1));
            unsigned short l2 = bf_hi(v.z - bf_f(h2)), l3 = bf_hi(v.w - bf_f(h3));
            *reinterpret_cast<uint2*>(&Ah[p * 16 + am][aq]) =
                make_uint2((unsigned)h0 | ((unsigned)h1 << 16), (unsigned)h2 | ((unsigned)h3 << 16));
            *reinterpret_cast<uint2*>(&Al[p * 16 + am][aq]) =
                make_uint2((unsigned)l0 | ((unsigned)l1 << 16), (unsigned)l2 | ((unsigned)l3 << 16));
        }
#pragma unroll
        for (int p = 0; p < 4; ++p) {
            *reinterpret_cast<uint4*>(&Bh[p * 32 + bn][bc]) = pbh[p];
            *reinterpret_cast<uint4*>(&Bl[p * 32 + bn][bc]) = pbl[p];
        }
        __syncthreads();
        if (s + 1 < 8) {
            int k0 = (s + 1) * 64;
#pragma unroll
            for (int p = 0; p < 8; ++p)
                pa[p] = *reinterpret_cast<const float4*>(&in[(size_t)(m0 + p * 16 + am) * DIM + k0 + aq]);
#pragma unroll
            for (int p = 0; p < 4; ++p) {
                pbh[p] = *reinterpret_cast<const uint4*>(&WCth[(size_t)(n0 + p * 32 + bn) * DIM + k0 + bc]);
                pbl[p] = *reinterpret_cast<const uint4*>(&WCtl[(size_t)(n0 + p * 32 + bn) * DIM + k0 + bc]);
            }
        }
#pragma unroll
        for (int k2 = 0; k2 < 2; ++k2) {
            int ko = k2 * 32 + kg * 8;
            bf16x8 ah[4], al4[4], bh4[4], bl4[4];
#pragma unroll
            for (int f = 0; f < 4; ++f) {
                ah[f]  = *reinterpret_cast<const bf16x8*>(&Ah[wr + f * 16 + fr][ko]);
                al4[f] = *reinterpret_cast<const bf16x8*>(&Al[wr + f * 16 + fr][ko]);
                bh4[f] = *reinterpret_cast<const bf16x8*>(&Bh[wc + f * 16 + fr][ko]);
                bl4[f] = *reinterpret_cast<const bf16x8*>(&Bl[wc + f * 16 + fr][ko]);
            }
#pragma unroll
            for (int i = 0; i < 4; ++i)
#pragma unroll
                for (int j = 0; j < 4; ++j) {
                    f32x4 c = acc[i][j];
                    c = __builtin_amdgcn_mfma_f32_16x16x32_bf16(ah[i],  bh4[j], c, 0, 0, 0);
                    c = __builtin_amdgcn_mfma_f32_16x16x32_bf16(ah[i],  bl4[j], c, 0, 0, 0);
                    c = __builtin_amdgcn_mfma_f32_16x16x32_bf16(al4[i], bh4[j], c, 0, 0, 0);
                    acc[i][j] = c;
                }
        }
    }
#pragma unroll
    for (int j = 0; j < 4; ++j) {
        int col = n0 + wc + j * 16 + fr;
        float bb = bias[col];
#pragma unroll
        for (int i = 0; i < 4; ++i) {
            int row = m0 + wr + i * 16 + kg * 4;
#pragma unroll
            for (int r = 0; r < 4; ++r)
                out[(size_t)(row + r) * DIM + col] = acc[i][j][r] - bb;
        }
    }
}

// ---------------------------------------------------------------------------
// Fallback chain (if cooperative launch is rejected): same stages, separate launches.
__global__ __launch_bounds__(256) void tile_gemm_k(const float* __restrict__ A, int ta,
                                                   const float* __restrict__ B,
                                                   float* C, int mode, float* ws) {
    gemm_tile(A, ta, B, C, blockIdx.x, mode, ws);
}
__global__ __launch_bounds__(256) void mirror_k(float* ws) {
    float* G = ws + OFF_G;
    int gtid = blockIdx.x * 256 + threadIdx.x;
#pragma unroll
    for (int e = 0; e < 4; ++e) {
        int idx = gtid * 4 + e;
        int i = idx >> 9, j = idx & 511;
        if (i < j) G[(size_t)j * DIM + i] = G[idx];
    }
}
__global__ __launch_bounds__(256) void mh_k(float* ws, const float* __restrict__ W) {
    float* cs = ws + OFF_CS; float* mh = ws + OFF_MH;
    int c = blockIdx.x * 256 + threadIdx.x;
    float s = 0.f;
    for (int k = 0; k < DIM; ++k) s = fmaf(cs[k], W[(size_t)k * DIM + c], s);
    mh[c] = s * INV_N;
}
__global__ __launch_bounds__(256) void trmh_k(float* ws) {
    __shared__ float red[256];
    float* mh = ws + OFF_MH;
    int t = threadIdx.x;
    red[t] = mh[t] * mh[t] + mh[t + 256] * mh[t + 256];
    __syncthreads();
    for (int o = 128; o > 0; o >>= 1) { if (t < o) red[t] += red[t + o]; __syncthreads(); }
    if (t == 0) atomicAdd(ws + OFF_SCAL, 51.2f - red[0]);
}
__global__ __launch_bounds__(256) void makeSP_k(float* ws) {
    float* CV = ws + OFF_CV; float* mh = ws + OFF_MH;
    float* S = ws + OFF_S;   float* P = ws + OFF_P;
    float invtr = 1.0f / ws[OFF_SCAL];
    int gtid = blockIdx.x * 256 + threadIdx.x;
#pragma unroll
    for (int e = 0; e < 4; ++e) {
        int idx = gtid * 4 + e;
        int i = idx >> 9, j = idx & 511;
        float v = CV[idx] * INV_N - mh[i] * mh[j] + ((i == j) ? INV_TEMP : 0.f);
        S[idx] = v * invtr;
        P[idx] = (i == j) ? 1.f : 0.f;
    }
}
__global__ __launch_bounds__(256) void bias_k(float* ws) {
    float* mh = ws + OFF_MH; float* P = ws + OFF_P; float* bias = ws + OFF_BIAS;
    float istr = 1.0f / sqrtf(ws[OFF_SCAL]);
    int c = blockIdx.x * 256 + threadIdx.x;
    float s = 0.f;
    for (int k = 0; k < DIM; ++k) s = fmaf(mh[k], P[(size_t)k * DIM + c], s);
    bias[c] = s * istr;
}

// ---------------------------------------------------------------------------
extern "C" void kernel_launch(void* const* d_in, const int* in_sizes, int n_in,
                              void* d_out, int out_size, void* d_ws, size_t ws_size,
                              hipStream_t stream) {
    (void)in_sizes; (void)n_in; (void)out_size; (void)ws_size;
    const float* x = (const float*)d_in[0];
    const float* Wl[3] = {(const float*)d_in[1], (const float*)d_in[2], (const float*)d_in[3]};
    float* out = (float*)d_out;
    float* ws  = (float*)d_ws;

    for (int l = 0; l < 3; ++l) {
        const float* in = (l == 0) ? x : out + (size_t)(l - 1) * NROWS * DIM;
        const float* W  = Wl[l];
        float* o = out + (size_t)l * NROWS * DIM;

        zero_k<<<257, 256, 0, stream>>>(ws);
        gram_k<<<dim3(10, 32), 256, 0, stream>>>(in, ws + OFF_G, ws + OFF_CS);

        float* wsp = ws;
        const float* wp = W;
        void* cargs[2] = {(void*)&wsp, (void*)&wp};
        hipError_t ce = hipLaunchCooperativeKernel((void*)coop_k, dim3(256), dim3(256),
                                                   cargs, 0, stream);
        if (ce != hipSuccess) {
            // Fallback: identical math via separate launches.
            mirror_k<<<256, 256, 0, stream>>>(ws);
            tile_gemm_k<<<256, 256, 0, stream>>>(ws + OFF_G, 0, W, ws + OFF_T1, 0, ws);
            mh_k<<<2, 256, 0, stream>>>(ws, W);
            tile_gemm_k<<<256, 256, 0, stream>>>(W, 1, ws + OFF_T1, ws + OFF_CV, 2, ws);
            trmh_k<<<1, 256, 0, stream>>>(ws);
            makeSP_k<<<256, 256, 0, stream>>>(ws);
            for (int it = 0; it < T_ITERS; ++it) {
                tile_gemm_k<<<256, 256, 0, stream>>>(ws + OFF_P, 0, ws + OFF_P, ws + OFF_T1, 0, ws);
                tile_gemm_k<<<256, 256, 0, stream>>>(ws + OFF_P, 0, ws + OFF_S, ws + OFF_T2, 0, ws);
                tile_gemm_k<<<256, 256, 0, stream>>>(ws + OFF_T1, 0, ws + OFF_T2, ws + OFF_P, 1, ws);
            }
            tile_gemm_k<<<256, 256, 0, stream>>>(W, 0, ws + OFF_P, nullptr, 3, ws);
            bias_k<<<2, 256, 0, stream>>>(ws);
        }

        out_k<<<dim3(4, 512), 256, 0, stream>>>(in,
            (const unsigned short*)(ws + OFF_WCH), (const unsigned short*)(ws + OFF_WCL),
            ws + OFF_BIAS, o);
    }
}